// Round 2
// baseline (106.484 us; speedup 1.0000x reference)
//
#include <hip/hip_runtime.h>

#define BB 64
#define NN 64
#define TT 100
#define S_TOT (NN * TT)

// One block (= one wave of 64 threads) per slice s = t*NN + n.
// Thread b handles batch-agent b: transform to world, all-pairs argmin
// over the 64 batch entries, neighbor select, accumulate loss term.
__global__ __launch_bounds__(64) void social_loss_kernel(
    const float* __restrict__ x,          // (B, N, T, 6) f32
    const float* __restrict__ wfa,        // (B, 3, 3)    f32
    const int* __restrict__ rand_idx,     // (T*N, B)     i32 in [0, B-2]
    const int* __restrict__ drop_mask,    // (T*N, B)     bool stored as i32
    float* __restrict__ out)              // (B, N) f32, pre-zeroed
{
    const int s = blockIdx.x;     // 0..6399
    const int b = threadIdx.x;    // 0..63
    const int t = s / NN;
    const int n = s - t * NN;

    // world_from_agent row-major (B,3,3): R = [:, :2, :2], trans = [:, :2, 2]
    const float* w = wfa + b * 9;
    const float r00 = w[0], r01 = w[1], tx = w[2];
    const float r10 = w[3], r11 = w[4], ty = w[5];

    // pos = x[b, n, t, 0:2]
    const size_t xoff = (((size_t)b * NN + n) * (size_t)TT + (size_t)t) * 6;
    const float px = x[xoff];
    const float py = x[xoff + 1];

    // pos_g[b,n,t,i] = R[b,i,0]*px + R[b,i,1]*py + t[b,i]
    const float gx = r00 * px + r01 * py + tx;
    const float gy = r10 * px + r11 * py + ty;
    const float sq = gx * gx + gy * gy;

    __shared__ float4 P[BB];
    P[b] = make_float4(gx, gy, sq, 0.0f);
    __syncthreads();

    // argmin_c dist[b,c], diagonal = inf, first-index tie rule via strict <
    float best = 3.4e38f;
    int besti = 0;
    #pragma unroll 16
    for (int c = 0; c < BB; ++c) {
        const float4 q = P[c];
        const float dot = fmaf(gx, q.x, gy * q.y);
        float d2 = fmaf(-2.0f, dot, sq + q.z);   // (sq_b + sq_c) - 2*dot, ref order
        d2 = fmaxf(d2, 1e-12f);
        if ((c != b) && (d2 < best)) { best = d2; besti = c; }
    }

    const size_t sb = (size_t)s * BB + b;
    const int r = rand_idx[sb];
    const int rnb = r + (r >= b ? 1 : 0);        // skip-self remap
    const int nb = drop_mask[sb] ? rnb : besti;

    const float4 q = P[nb];
    const float dot = fmaf(gx, q.x, gy * q.y);
    const float d2 = fmaxf(fmaf(-2.0f, dot, sq + q.z), 1e-12f);
    const float nd = sqrtf(d2);
    const float diff = nd - 1.5f;

    // loss[b,n] = mean_t (nd - 1.5)^2 ; 64 lanes -> 64 distinct cache lines
    atomicAdd(&out[b * NN + n], diff * diff * (1.0f / TT));
}

extern "C" void kernel_launch(void* const* d_in, const int* in_sizes, int n_in,
                              void* d_out, int out_size, void* d_ws, size_t ws_size,
                              hipStream_t stream) {
    const float* x = (const float*)d_in[0];
    const float* wfa = (const float*)d_in[1];
    const int* rand_idx = (const int*)d_in[2];
    const int* drop_mask = (const int*)d_in[3];
    float* out = (float*)d_out;

    // d_out is re-poisoned (0xAA) before every timed launch — zero it.
    hipMemsetAsync(out, 0, (size_t)out_size * sizeof(float), stream);

    social_loss_kernel<<<S_TOT, 64, 0, stream>>>(x, wfa, rand_idx, drop_mask, out);
}